// Round 10
// baseline (224.300 us; speedup 1.0000x reference)
//
#include <hip/hip_runtime.h>
#include <string.h>

typedef _Float16 half2v __attribute__((ext_vector_type(2)));
typedef _Float16 half4  __attribute__((ext_vector_type(4)));
typedef _Float16 half8  __attribute__((ext_vector_type(8)));
typedef float    float4v __attribute__((ext_vector_type(4)));
typedef unsigned int uint4v __attribute__((ext_vector_type(4)));

#define HH 256
#define WW 256
#define HSTR 264   // R5-proven h_lds row stride (do NOT change; 268 measured slower)

static __device__ inline half2v pkrtz(float a, float b) {
    return __builtin_bit_cast(half2v, __builtin_amdgcn_cvt_pkrtz(a, b));
}

static __device__ inline float fdot2f(half2v a, half2v b, float c) {
#if __has_builtin(__builtin_amdgcn_fdot2)
    return __builtin_amdgcn_fdot2(__builtin_bit_cast(__fp16 __attribute__((ext_vector_type(2))), a),
                                  __builtin_bit_cast(__fp16 __attribute__((ext_vector_type(2))), b),
                                  c, false);
#else
    return c + (float)a[0] * (float)b[0] + (float)a[1] * (float)b[1];
#endif
}

// ---------------- x (NCHW f32, 3ch) -> xh (NHWC f16, 16ch zero-padded) -----
__global__ __launch_bounds__(256) void xcvt(
    const float* __restrict__ x, _Float16* __restrict__ xh)
{
    int gid = blockIdx.x * 256 + threadIdx.x;      // n*65536 + y*256 + x
    int px = gid & 65535, n = gid >> 16;
    float r = x[n * 196608 + px];
    float g = x[n * 196608 + 65536 + px];
    float b = x[n * 196608 + 131072 + px];
    half2v p0 = pkrtz(r, g);
    half2v p1 = pkrtz(b, 0.f);
    unsigned u0, u1;
    memcpy(&u0, &p0, 4); memcpy(&u1, &p1, 4);
    uint4v v0 = {u0, u1, 0u, 0u};
    uint4v v1 = {0u, 0u, 0u, 0u};
    uint4v* dst = (uint4v*)&xh[(long)gid * 16];
    dst[0] = v0; dst[1] = v1;
}

// ---------------- fused weight packing (w2/b2 + conv layers) ---------------
__global__ __launch_bounds__(256) void pack_all(
    const float* __restrict__ w2, const float* __restrict__ b2,
    half8* __restrict__ w2p, float* __restrict__ b2p,
    const float* __restrict__ w0, const float* __restrict__ w1c,
    const float* __restrict__ w2c, const float* __restrict__ w3c,
    half8* __restrict__ wpk)
{
    int tid = blockIdx.x * 256 + threadIdx.x;
    if (tid < 13824) {
        int l  = tid & 63;
        int s  = (tid >> 6) & 7;
        int tt = tid >> 9;                           // tile 0..26
        int kk = tt / 3, c = tt % 3;
        int ci = l & 15;
        int col = (ci * 9 + kk) * 3 + c;
        int kbase = s * 32 + (l >> 4) * 8;
        half8 h;
#pragma unroll
        for (int j = 0; j < 8; ++j)
            h[j] = (_Float16)w2[(kbase + j) * 432 + col];
        w2p[tid] = h;

        if (tid < 432) {
            int tt2 = tid >> 4, ci2 = tid & 15;
            int kk2 = tt2 / 3, c2 = tt2 % 3;
            b2p[tid] = b2[(ci2 * 9 + kk2) * 3 + c2];
        }
    } else if (tid < 15104) {
        int t2 = tid - 13824;                        // < 1280
        int l = t2 & 63, s = (t2 >> 6) % 5, cv = t2 / 320;
        const float* w = (cv == 0) ? w0 : (cv == 1) ? w1c : (cv == 2) ? w2c : w3c;
        int CIN = (cv == 0) ? 3 : 16;
        int o = l & 15, hi = l >> 4;
        half8 h;
#pragma unroll
        for (int j = 0; j < 8; ++j) {
            int k = 32 * s + hi * 8 + j;
            int tap = k >> 4, ci = k & 15;
            float v = 0.f;
            if (tap < 9 && ci < CIN)
                v = w[((o * CIN + ci) * 3 + tap / 3) * 3 + tap % 3];
            h[j] = (_Float16)v;
        }
        wpk[t2] = h;
    }
}

// ---------------- conv 3x3 + ReLU via implicit-GEMM MFMA, NHWC f16 ---------
__global__ __launch_bounds__(256) void conv_mfma(
    const _Float16* __restrict__ in, const half8* __restrict__ wpk,
    const float* __restrict__ bias, _Float16* __restrict__ outp)
{
    __shared__ _Float16 tile[7][66][16];           // 14784 B

    const int t = threadIdx.x;
    const int bid = blockIdx.x;
    const int xt = bid & 3, yt = (bid >> 2) & 63, n = bid >> 8;
    const int x0 = xt * 64, y0 = yt * 4;

    for (int e = t; e < 462; e += 256) {           // 7 rows x 66 x, 32B chunks
        int xx = e % 66, row = e / 66;
        int gy = y0 + row - 1, gx = x0 + xx - 1;
        uint4v v0 = {0u,0u,0u,0u}, v1 = {0u,0u,0u,0u};
        if (gy >= 0 && gy < HH && gx >= 0 && gx < WW) {
            const uint4v* src = (const uint4v*)&in[(((long)(n*HH+gy))*WW + gx) * 16];
            v0 = src[0]; v1 = src[1];
        }
        uint4v* dst = (uint4v*)&tile[row][xx][0];
        dst[0] = v0; dst[1] = v1;
    }
    __syncthreads();

    const int wid = t >> 6, lane = t & 63;
    const int l15 = lane & 15, hi = lane >> 4;

    half8 af[5];
#pragma unroll
    for (int s = 0; s < 5; ++s) af[s] = wpk[s * 64 + lane];
    const float4v bini = *(const float4v*)&bias[hi * 4];

    const int ty = wid;
    const half8* bp = (const half8*)&tile[0][0][0];
#pragma unroll
    for (int tx = 0; tx < 4; ++tx) {
        float4v acc = bini;
#pragma unroll
        for (int s = 0; s < 5; ++s) {
            int tap = 2 * s + (hi >> 1);
            int dyq = (tap * 11) >> 5;             // tap / 3
            int dxr = tap - dyq * 3;
            int cell = (ty + dyq) * 66 + (tx * 16 + l15 + dxr);
            half8 bf = bp[cell * 2 + (hi & 1)];
            acc = __builtin_amdgcn_mfma_f32_16x16x32_f16(af[s], bf, acc, 0, 0, 0);
        }
        int gx = x0 + tx * 16 + l15, gy = y0 + ty;
        half2v p0 = pkrtz(fmaxf(acc[0], 0.f), fmaxf(acc[1], 0.f));
        half2v p1 = pkrtz(fmaxf(acc[2], 0.f), fmaxf(acc[3], 0.f));
        half4 ov = __builtin_shufflevector(p0, p1, 0, 1, 2, 3);
        *(half4*)&outp[(((long)(n*HH+gy))*WW + gx) * 16 + hi * 4] = ov;
    }
}

// ---- fused Pos2Weight MLP (MFMA) + locally-connected contraction ----------
// Verbatim R5 structure (mlp=150us proven) with ONE change: the ks-loop is
// 1-deep software-pipelined (prefetch afrag+bfrag of ks+1 during ks's MFMAs).
// launch_bounds(512,2) so the +32 live VGPR cannot spill (R6 lesson).
__global__ __launch_bounds__(512, 2) void mlp_lc_mfma(
    const float* __restrict__ pos, const float* __restrict__ w1,
    const float* __restrict__ b1,  const half8* __restrict__ w2p,
    const float* __restrict__ b2p, const _Float16* __restrict__ f,
    float* __restrict__ out)
{
    __shared__ __attribute__((aligned(16))) char smem[47872];
    _Float16* h_lds    = (_Float16*)smem;                  // [64][264] 33792 B
    _Float16* f_lds    = (_Float16*)(smem + 33792);        // 408 cells x16h, 13056 B
    float*    pos_lds  = (float*)(smem + 33792 + 13056);   // [64][4] 1024 B
    float*    part_lds = (float*)smem;                     // [64][106] alias

    const int t = threadIdx.x;
    // XCD-chunked swizzle: each XCD owns a contiguous slab of logical work
    const int bid = blockIdx.x;
    const int lb  = (bid & 7) * 512 + (bid >> 3);
    const int p0  = lb * 64;
    const int t2  = p0 >> 9;                  // output row oy
    const int hh  = t2 >> 1;
    const int ww0 = (p0 >> 1) & (WW - 1);

    if (t < 192) pos_lds[(t / 3) * 4 + (t % 3)] = pos[p0 * 3 + t];

    // stage f (f16 NHWC): 408 chunks = 4n x 3dy x 34x, one 32B chunk/thread
    if (t < 408) {
        int x = t % 34, nd = t / 34;
        int dy = nd % 3, n = nd / 3;
        int gy = hh + dy - 1, gx = ww0 + x - 1;
        uint4v v0 = {0u,0u,0u,0u}, v1 = {0u,0u,0u,0u};
        if (gy >= 0 && gy < HH && gx >= 0 && gx < WW) {
            const uint4v* src = (const uint4v*)&f[(((long)(n*HH+gy))*WW + gx) * 16];
            v0 = src[0]; v1 = src[1];
        }
        int cell = (((dy * 34 + x) * 4) + n) ^ (x & 7);
        uint4v* dst = (uint4v*)&f_lds[cell * 16];
        dst[0] = v0; dst[1] = v1;
    }
    __syncthreads();

    // ---- h = relu(pos @ w1 + b1), f16, padded stride 264 ----
    {
        const int k  = t & 255;
        const int i0 = (t >> 8) * 32;
        float wa = w1[k], wb = w1[256 + k], wc = w1[512 + k], bb = b1[k];
#pragma unroll 8
        for (int i = i0; i < i0 + 32; ++i) {
            float4v pv = *(const float4v*)&pos_lds[i * 4];
            float a = fmaf(pv[0], wa, fmaf(pv[1], wb, fmaf(pv[2], wc, bb)));
            h_lds[i * HSTR + k] = (_Float16)fmaxf(a, 0.f);
        }
    }
    __syncthreads();

    // ---- GEMM: acc[tt][pg] = w2tile(tb+tt)^T @ h(pg), 1-deep pipeline ----
    const int wid  = t >> 6;
    const int lane = t & 63;
    const int l15  = lane & 15, hi = lane >> 4;
    const int tb   = (wid <= 3) ? wid * 4 : 12 + (wid - 3) * 3;
    const int cnt  = (wid < 3) ? 4 : 3;

    float4v acc[4][4];
#pragma unroll
    for (int tt = 0; tt < 4; ++tt)
        if (tt < cnt) {
            float4v binit = *(const float4v*)&b2p[(tb + tt) * 16 + hi * 4];
#pragma unroll
            for (int pg = 0; pg < 4; ++pg) acc[tt][pg] = binit;
        }

    const half8* w2base = w2p + tb * 8 * 64 + lane;
    const _Float16* hbase = &h_lds[l15 * HSTR + hi * 8];

    half8 afn[4], bfn[4];
#pragma unroll
    for (int pg = 0; pg < 4; ++pg)
        bfn[pg] = *(const half8*)&hbase[pg * 16 * HSTR];
#pragma unroll
    for (int tt = 0; tt < 4; ++tt)
        if (tt < cnt) afn[tt] = w2base[tt * 8 * 64];

    for (int ks = 0; ks < 8; ++ks) {
        half8 afc[4], bfc[4];
#pragma unroll
        for (int tt = 0; tt < 4; ++tt) afc[tt] = afn[tt];
#pragma unroll
        for (int pg = 0; pg < 4; ++pg) bfc[pg] = bfn[pg];
        if (ks < 7) {
#pragma unroll
            for (int pg = 0; pg < 4; ++pg)
                bfn[pg] = *(const half8*)&hbase[pg * 16 * HSTR + (ks + 1) * 32];
#pragma unroll
            for (int tt = 0; tt < 4; ++tt)
                if (tt < cnt) afn[tt] = w2base[(tt * 8 + ks + 1) * 64];
        }
#pragma unroll
        for (int tt = 0; tt < 4; ++tt)
            if (tt < cnt) {
#pragma unroll
                for (int pg = 0; pg < 4; ++pg)
                    acc[tt][pg] = __builtin_amdgcn_mfma_f32_16x16x32_f16(
                        afc[tt], bfc[pg], acc[tt][pg], 0, 0, 0);
            }
    }
    __syncthreads();   // all h reads done; part_lds (alias) may be written

    // ---- epilogue: dot2 contraction with f, reduce over hi and waves ------
    const int r3 = tb % 3;            // wave-uniform rgb rotation
    int dy_t[4], dx_t[4];
#pragma unroll
    for (int tt = 0; tt < 4; ++tt) {
        int kk = (tb + tt) / 3;
        dy_t[tt] = kk / 3;
        dx_t[tt] = kk % 3;
    }

#pragma unroll
    for (int pg = 0; pg < 4; ++pg) {
        const int posl = pg * 16 + l15;
        const int xloc = posl >> 1;

        float part[4][3];
#pragma unroll
        for (int n = 0; n < 4; ++n)
#pragma unroll
            for (int c = 0; c < 3; ++c) part[n][c] = 0.f;

#pragma unroll
        for (int tt = 0; tt < 4; ++tt)
            if (tt < cnt) {
                int x    = xloc + dx_t[tt];
                int key  = x & 7;
                int b4   = (dy_t[tt] * 34 + x) * 4;
                int basc = ((b4 ^ (key & 4)) << 4) + hi * 4;  // halfs
                int kn3  = (key & 3) << 4;
                half2v ap = pkrtz(acc[tt][pg][0], acc[tt][pg][1]);
                half2v bq = pkrtz(acc[tt][pg][2], acc[tt][pg][3]);
                const int u = tt % 3;
#pragma unroll
                for (int n = 0; n < 4; ++n) {
                    half4 fv = *(const half4*)&f_lds[basc + ((n << 4) ^ kn3)];
                    half2v flo = __builtin_shufflevector(fv, fv, 0, 1);
                    half2v fhi = __builtin_shufflevector(fv, fv, 2, 3);
                    part[n][u] = fdot2f(flo, ap, fdot2f(fhi, bq, part[n][u]));
                }
            }

        float real[4][3];
        if (r3 == 0) {
#pragma unroll
            for (int n = 0; n < 4; ++n) {
                real[n][0] = part[n][0]; real[n][1] = part[n][1]; real[n][2] = part[n][2];
            }
        } else if (r3 == 1) {
#pragma unroll
            for (int n = 0; n < 4; ++n) {
                real[n][1] = part[n][0]; real[n][2] = part[n][1]; real[n][0] = part[n][2];
            }
        } else {
#pragma unroll
            for (int n = 0; n < 4; ++n) {
                real[n][2] = part[n][0]; real[n][0] = part[n][1]; real[n][1] = part[n][2];
            }
        }

#pragma unroll
        for (int n = 0; n < 4; ++n)
#pragma unroll
            for (int c = 0; c < 3; ++c) {
                float v = real[n][c];
                v += __shfl_xor(v, 16);
                v += __shfl_xor(v, 32);
                if (hi == 0)
                    part_lds[posl * 106 + (n * 3 + c) * 8 + wid] = v;
            }
    }
    __syncthreads();

    // ---- combine 8 waves' partials, add mean, store ----
    for (int e = t; e < 768; e += 512) {
        int posl = e & 63;
        int j = e >> 6;                       // n*3+c
        const float* pr = &part_lds[posl * 106 + j * 8];
        float4v v0 = *(const float4v*)pr;
        float4v v1 = *(const float4v*)(pr + 4);
        float v = v0[0] + v0[1] + v0[2] + v0[3] + v1[0] + v1[1] + v1[2] + v1[3];
        int n = j / 3, c = j - 3 * n;
        float mean = (c == 0) ? 114.4440f : (c == 1) ? 111.4605f : 103.0200f;
        out[((n * 3 + c) * 512 + t2) * 512 + (ww0 * 2 + posl)] = v + mean;
    }
}

extern "C" void kernel_launch(void* const* d_in, const int* in_sizes, int n_in,
                              void* d_out, int out_size, void* d_ws, size_t ws_size,
                              hipStream_t stream) {
    const float* x    = (const float*)d_in[0];
    const float* pos  = (const float*)d_in[1];
    const float* c0w  = (const float*)d_in[2];
    const float* c1w  = (const float*)d_in[4];
    const float* c2w  = (const float*)d_in[6];
    const float* c3w  = (const float*)d_in[8];
    const float* c0b  = (const float*)d_in[3];
    const float* c1b  = (const float*)d_in[5];
    const float* c2b  = (const float*)d_in[7];
    const float* c3b  = (const float*)d_in[9];
    const float* w1   = (const float*)d_in[10];
    const float* b1   = (const float*)d_in[11];
    const float* w2   = (const float*)d_in[12];
    const float* b2   = (const float*)d_in[13];
    float* out = (float*)d_out;

    char* ws = (char*)d_ws;
    _Float16* xh = (_Float16*)ws;                         // 8 MB
    _Float16* fA = (_Float16*)(ws + (8u << 20));          // 8 MB
    _Float16* fB = (_Float16*)(ws + (16u << 20));         // 8 MB
    half8* w2p   = (half8*)(ws + (24u << 20));            // 221184 B
    float* b2p   = (float*)(ws + (24u << 20) + 221184);   // 1728 B
    half8* wpk   = (half8*)(ws + (24u << 20) + 221184 + 1728);  // 20480 B

    xcvt<<<1024, 256, 0, stream>>>(x, xh);
    pack_all<<<59, 256, 0, stream>>>(w2, b2, w2p, b2p, c0w, c1w, c2w, c3w, wpk);

    conv_mfma<<<1024, 256, 0, stream>>>(xh, wpk,         c0b, fA);
    conv_mfma<<<1024, 256, 0, stream>>>(fA, wpk + 320,   c1b, fB);
    conv_mfma<<<1024, 256, 0, stream>>>(fB, wpk + 640,   c2b, fA);
    conv_mfma<<<1024, 256, 0, stream>>>(fA, wpk + 960,   c3b, fB);

    mlp_lc_mfma<<<4096, 512, 0, stream>>>(pos, w1, b1, w2p, b2p, fB, out);
}

// Round 11
// 158.193 us; speedup vs baseline: 1.4179x; 1.4179x over previous
//
#include <hip/hip_runtime.h>
#include <string.h>

typedef _Float16 half2v __attribute__((ext_vector_type(2)));
typedef _Float16 half4  __attribute__((ext_vector_type(4)));
typedef _Float16 half8  __attribute__((ext_vector_type(8)));
typedef float    float4v __attribute__((ext_vector_type(4)));
typedef unsigned int uint4v __attribute__((ext_vector_type(4)));

#define HH 256
#define WW 256
#define HSTR 264   // R5-proven h_lds row stride (268 measured slower — R9)

static __device__ inline half2v pkrtz(float a, float b) {
    return __builtin_bit_cast(half2v, __builtin_amdgcn_cvt_pkrtz(a, b));
}

static __device__ inline float fdot2f(half2v a, half2v b, float c) {
#if __has_builtin(__builtin_amdgcn_fdot2)
    return __builtin_amdgcn_fdot2(__builtin_bit_cast(__fp16 __attribute__((ext_vector_type(2))), a),
                                  __builtin_bit_cast(__fp16 __attribute__((ext_vector_type(2))), b),
                                  c, false);
#else
    return c + (float)a[0] * (float)b[0] + (float)a[1] * (float)b[1];
#endif
}

// ---------------- x (NCHW f32, 3ch) -> xh (NHWC f16, 16ch zero-padded) -----
__global__ __launch_bounds__(256) void xcvt(
    const float* __restrict__ x, _Float16* __restrict__ xh)
{
    int gid = blockIdx.x * 256 + threadIdx.x;      // n*65536 + y*256 + x
    int px = gid & 65535, n = gid >> 16;
    float r = x[n * 196608 + px];
    float g = x[n * 196608 + 65536 + px];
    float b = x[n * 196608 + 131072 + px];
    half2v p0 = pkrtz(r, g);
    half2v p1 = pkrtz(b, 0.f);
    unsigned u0, u1;
    memcpy(&u0, &p0, 4); memcpy(&u1, &p1, 4);
    uint4v v0 = {u0, u1, 0u, 0u};
    uint4v v1 = {0u, 0u, 0u, 0u};
    uint4v* dst = (uint4v*)&xh[(long)gid * 16];
    dst[0] = v0; dst[1] = v1;
}

// ---------------- fused weight packing (w2/b2 + conv layers) ---------------
__global__ __launch_bounds__(256) void pack_all(
    const float* __restrict__ w2, const float* __restrict__ b2,
    half8* __restrict__ w2p, float* __restrict__ b2p,
    const float* __restrict__ w0, const float* __restrict__ w1c,
    const float* __restrict__ w2c, const float* __restrict__ w3c,
    half8* __restrict__ wpk)
{
    int tid = blockIdx.x * 256 + threadIdx.x;
    if (tid < 13824) {
        int l  = tid & 63;
        int s  = (tid >> 6) & 7;
        int tt = tid >> 9;                           // tile 0..26
        int kk = tt / 3, c = tt % 3;
        int ci = l & 15;
        int col = (ci * 9 + kk) * 3 + c;
        int kbase = s * 32 + (l >> 4) * 8;
        half8 h;
#pragma unroll
        for (int j = 0; j < 8; ++j)
            h[j] = (_Float16)w2[(kbase + j) * 432 + col];
        w2p[tid] = h;

        if (tid < 432) {
            int tt2 = tid >> 4, ci2 = tid & 15;
            int kk2 = tt2 / 3, c2 = tt2 % 3;
            b2p[tid] = b2[(ci2 * 9 + kk2) * 3 + c2];
        }
    } else if (tid < 15104) {
        int t2 = tid - 13824;                        // < 1280
        int l = t2 & 63, s = (t2 >> 6) % 5, cv = t2 / 320;
        const float* w = (cv == 0) ? w0 : (cv == 1) ? w1c : (cv == 2) ? w2c : w3c;
        int CIN = (cv == 0) ? 3 : 16;
        int o = l & 15, hi = l >> 4;
        half8 h;
#pragma unroll
        for (int j = 0; j < 8; ++j) {
            int k = 32 * s + hi * 8 + j;
            int tap = k >> 4, ci = k & 15;
            float v = 0.f;
            if (tap < 9 && ci < CIN)
                v = w[((o * CIN + ci) * 3 + tap / 3) * 3 + tap % 3];
            h[j] = (_Float16)v;
        }
        wpk[t2] = h;
    }
}

// ---------------- conv 3x3 + ReLU via implicit-GEMM MFMA, NHWC f16 ---------
__global__ __launch_bounds__(256) void conv_mfma(
    const _Float16* __restrict__ in, const half8* __restrict__ wpk,
    const float* __restrict__ bias, _Float16* __restrict__ outp)
{
    __shared__ _Float16 tile[7][66][16];           // 14784 B

    const int t = threadIdx.x;
    const int bid = blockIdx.x;
    const int xt = bid & 3, yt = (bid >> 2) & 63, n = bid >> 8;
    const int x0 = xt * 64, y0 = yt * 4;

    for (int e = t; e < 462; e += 256) {           // 7 rows x 66 x, 32B chunks
        int xx = e % 66, row = e / 66;
        int gy = y0 + row - 1, gx = x0 + xx - 1;
        uint4v v0 = {0u,0u,0u,0u}, v1 = {0u,0u,0u,0u};
        if (gy >= 0 && gy < HH && gx >= 0 && gx < WW) {
            const uint4v* src = (const uint4v*)&in[(((long)(n*HH+gy))*WW + gx) * 16];
            v0 = src[0]; v1 = src[1];
        }
        uint4v* dst = (uint4v*)&tile[row][xx][0];
        dst[0] = v0; dst[1] = v1;
    }
    __syncthreads();

    const int wid = t >> 6, lane = t & 63;
    const int l15 = lane & 15, hi = lane >> 4;

    half8 af[5];
#pragma unroll
    for (int s = 0; s < 5; ++s) af[s] = wpk[s * 64 + lane];
    const float4v bini = *(const float4v*)&bias[hi * 4];

    const int ty = wid;
    const half8* bp = (const half8*)&tile[0][0][0];
#pragma unroll
    for (int tx = 0; tx < 4; ++tx) {
        float4v acc = bini;
#pragma unroll
        for (int s = 0; s < 5; ++s) {
            int tap = 2 * s + (hi >> 1);
            int dyq = (tap * 11) >> 5;             // tap / 3
            int dxr = tap - dyq * 3;
            int cell = (ty + dyq) * 66 + (tx * 16 + l15 + dxr);
            half8 bf = bp[cell * 2 + (hi & 1)];
            acc = __builtin_amdgcn_mfma_f32_16x16x32_f16(af[s], bf, acc, 0, 0, 0);
        }
        int gx = x0 + tx * 16 + l15, gy = y0 + ty;
        half2v p0 = pkrtz(fmaxf(acc[0], 0.f), fmaxf(acc[1], 0.f));
        half2v p1 = pkrtz(fmaxf(acc[2], 0.f), fmaxf(acc[3], 0.f));
        half4 ov = __builtin_shufflevector(p0, p1, 0, 1, 2, 3);
        *(half4*)&outp[(((long)(n*HH+gy))*WW + gx) * 16 + hi * 4] = ov;
    }
}

// ---- fused Pos2Weight MLP (MFMA) + locally-connected contraction ----------
// R5 structure verbatim (mlp=150us proven; combined reg budget 64+64acc=128
// exactly fills 2-blocks/CU) with ONE change: h-phase computes 4 k x 8 pos
// per thread (b64 writes, 1/4 the DS ops, ~25% fewer VALU) using only
// transient registers.
__global__ __launch_bounds__(512, 4) void mlp_lc_mfma(
    const float* __restrict__ pos, const float* __restrict__ w1,
    const float* __restrict__ b1,  const half8* __restrict__ w2p,
    const float* __restrict__ b2p, const _Float16* __restrict__ f,
    float* __restrict__ out)
{
    __shared__ __attribute__((aligned(16))) char smem[47872];
    _Float16* h_lds    = (_Float16*)smem;                  // [64][264] 33792 B
    _Float16* f_lds    = (_Float16*)(smem + 33792);        // 408 cells x16h, 13056 B
    float*    pos_lds  = (float*)(smem + 33792 + 13056);   // [64][4] 1024 B
    float*    part_lds = (float*)smem;                     // [64][106] alias

    const int t = threadIdx.x;
    // XCD-chunked swizzle: each XCD owns a contiguous slab of logical work
    const int bid = blockIdx.x;
    const int lb  = (bid & 7) * 512 + (bid >> 3);
    const int p0  = lb * 64;
    const int t2  = p0 >> 9;                  // output row oy
    const int hh  = t2 >> 1;
    const int ww0 = (p0 >> 1) & (WW - 1);

    if (t < 192) pos_lds[(t / 3) * 4 + (t % 3)] = pos[p0 * 3 + t];

    // stage f (f16 NHWC): 408 chunks = 4n x 3dy x 34x, one 32B chunk/thread
    if (t < 408) {
        int x = t % 34, nd = t / 34;
        int dy = nd % 3, n = nd / 3;
        int gy = hh + dy - 1, gx = ww0 + x - 1;
        uint4v v0 = {0u,0u,0u,0u}, v1 = {0u,0u,0u,0u};
        if (gy >= 0 && gy < HH && gx >= 0 && gx < WW) {
            const uint4v* src = (const uint4v*)&f[(((long)(n*HH+gy))*WW + gx) * 16];
            v0 = src[0]; v1 = src[1];
        }
        int cell = (((dy * 34 + x) * 4) + n) ^ (x & 7);
        uint4v* dst = (uint4v*)&f_lds[cell * 16];
        dst[0] = v0; dst[1] = v1;
    }
    __syncthreads();                          // pos + f ready

    // ---- h = relu(pos @ w1 + b1): 4 k x 8 pos per thread, b64 writes ----
    {
        const int k4 = (t & 63) * 4;          // lane-contiguous k block
        const int i0 = (t >> 6) * 8;          // 8 positions per thread
        const float4v w1r0 = *(const float4v*)&w1[k4];
        const float4v w1r1 = *(const float4v*)&w1[256 + k4];
        const float4v w1r2 = *(const float4v*)&w1[512 + k4];
        const float4v b1v  = *(const float4v*)&b1[k4];
#pragma unroll
        for (int i = i0; i < i0 + 8; ++i) {
            float4v pv = *(const float4v*)&pos_lds[i * 4];
            float a0 = fmaf(pv[0], w1r0[0], fmaf(pv[1], w1r1[0], fmaf(pv[2], w1r2[0], b1v[0])));
            float a1 = fmaf(pv[0], w1r0[1], fmaf(pv[1], w1r1[1], fmaf(pv[2], w1r2[1], b1v[1])));
            float a2 = fmaf(pv[0], w1r0[2], fmaf(pv[1], w1r1[2], fmaf(pv[2], w1r2[2], b1v[2])));
            float a3 = fmaf(pv[0], w1r0[3], fmaf(pv[1], w1r1[3], fmaf(pv[2], w1r2[3], b1v[3])));
            half2v q0 = pkrtz(fmaxf(a0, 0.f), fmaxf(a1, 0.f));
            half2v q1 = pkrtz(fmaxf(a2, 0.f), fmaxf(a3, 0.f));
            *(half4*)&h_lds[i * HSTR + k4] = __builtin_shufflevector(q0, q1, 0, 1, 2, 3);
        }
    }
    __syncthreads();                          // h ready

    // ---- GEMM: acc[tt][pg] = w2tile(tb+tt)^T @ h(pg) ----
    const int wid  = t >> 6;
    const int lane = t & 63;
    const int l15  = lane & 15, hi = lane >> 4;
    const int tb   = (wid <= 3) ? wid * 4 : 12 + (wid - 3) * 3;
    const int cnt  = (wid < 3) ? 4 : 3;

    float4v acc[4][4];
#pragma unroll
    for (int tt = 0; tt < 4; ++tt)
        if (tt < cnt) {
            float4v binit = *(const float4v*)&b2p[(tb + tt) * 16 + hi * 4];
#pragma unroll
            for (int pg = 0; pg < 4; ++pg) acc[tt][pg] = binit;
        }

    for (int ks = 0; ks < 8; ++ks) {
        half8 bfrag[4];
#pragma unroll
        for (int pg = 0; pg < 4; ++pg)
            bfrag[pg] = *(const half8*)&h_lds[(pg * 16 + l15) * HSTR + ks * 32 + hi * 8];
#pragma unroll
        for (int tt = 0; tt < 4; ++tt)
            if (tt < cnt) {
                half8 afrag = w2p[((tb + tt) * 8 + ks) * 64 + lane];
#pragma unroll
                for (int pg = 0; pg < 4; ++pg)
                    acc[tt][pg] = __builtin_amdgcn_mfma_f32_16x16x32_f16(
                        afrag, bfrag[pg], acc[tt][pg], 0, 0, 0);
            }
    }
    __syncthreads();   // all h reads done; part_lds (alias) may be written

    // ---- epilogue: dot2 contraction with f, reduce over hi and waves ------
    const int r3 = tb % 3;            // wave-uniform rgb rotation
    int dy_t[4], dx_t[4];
#pragma unroll
    for (int tt = 0; tt < 4; ++tt) {
        int kk = (tb + tt) / 3;
        dy_t[tt] = kk / 3;
        dx_t[tt] = kk % 3;
    }

#pragma unroll
    for (int pg = 0; pg < 4; ++pg) {
        const int posl = pg * 16 + l15;
        const int xloc = posl >> 1;

        float part[4][3];
#pragma unroll
        for (int n = 0; n < 4; ++n)
#pragma unroll
            for (int c = 0; c < 3; ++c) part[n][c] = 0.f;

#pragma unroll
        for (int tt = 0; tt < 4; ++tt)
            if (tt < cnt) {
                int x    = xloc + dx_t[tt];
                int key  = x & 7;
                int b4   = (dy_t[tt] * 34 + x) * 4;
                int basc = ((b4 ^ (key & 4)) << 4) + hi * 4;  // halfs
                int kn3  = (key & 3) << 4;
                half2v ap = pkrtz(acc[tt][pg][0], acc[tt][pg][1]);
                half2v bq = pkrtz(acc[tt][pg][2], acc[tt][pg][3]);
                const int u = tt % 3;
#pragma unroll
                for (int n = 0; n < 4; ++n) {
                    half4 fv = *(const half4*)&f_lds[basc + ((n << 4) ^ kn3)];
                    half2v flo = __builtin_shufflevector(fv, fv, 0, 1);
                    half2v fhi = __builtin_shufflevector(fv, fv, 2, 3);
                    part[n][u] = fdot2f(flo, ap, fdot2f(fhi, bq, part[n][u]));
                }
            }

        float real[4][3];
        if (r3 == 0) {
#pragma unroll
            for (int n = 0; n < 4; ++n) {
                real[n][0] = part[n][0]; real[n][1] = part[n][1]; real[n][2] = part[n][2];
            }
        } else if (r3 == 1) {
#pragma unroll
            for (int n = 0; n < 4; ++n) {
                real[n][1] = part[n][0]; real[n][2] = part[n][1]; real[n][0] = part[n][2];
            }
        } else {
#pragma unroll
            for (int n = 0; n < 4; ++n) {
                real[n][2] = part[n][0]; real[n][0] = part[n][1]; real[n][1] = part[n][2];
            }
        }

#pragma unroll
        for (int n = 0; n < 4; ++n)
#pragma unroll
            for (int c = 0; c < 3; ++c) {
                float v = real[n][c];
                v += __shfl_xor(v, 16);
                v += __shfl_xor(v, 32);
                if (hi == 0)
                    part_lds[posl * 106 + (n * 3 + c) * 8 + wid] = v;
            }
    }
    __syncthreads();

    // ---- combine 8 waves' partials, add mean, store ----
    for (int e = t; e < 768; e += 512) {
        int posl = e & 63;
        int j = e >> 6;                       // n*3+c
        const float* pr = &part_lds[posl * 106 + j * 8];
        float4v v0 = *(const float4v*)pr;
        float4v v1 = *(const float4v*)(pr + 4);
        float v = v0[0] + v0[1] + v0[2] + v0[3] + v1[0] + v1[1] + v1[2] + v1[3];
        int n = j / 3, c = j - 3 * n;
        float mean = (c == 0) ? 114.4440f : (c == 1) ? 111.4605f : 103.0200f;
        out[((n * 3 + c) * 512 + t2) * 512 + (ww0 * 2 + posl)] = v + mean;
    }
}

extern "C" void kernel_launch(void* const* d_in, const int* in_sizes, int n_in,
                              void* d_out, int out_size, void* d_ws, size_t ws_size,
                              hipStream_t stream) {
    const float* x    = (const float*)d_in[0];
    const float* pos  = (const float*)d_in[1];
    const float* c0w  = (const float*)d_in[2];
    const float* c1w  = (const float*)d_in[4];
    const float* c2w  = (const float*)d_in[6];
    const float* c3w  = (const float*)d_in[8];
    const float* c0b  = (const float*)d_in[3];
    const float* c1b  = (const float*)d_in[5];
    const float* c2b  = (const float*)d_in[7];
    const float* c3b  = (const float*)d_in[9];
    const float* w1   = (const float*)d_in[10];
    const float* b1   = (const float*)d_in[11];
    const float* w2   = (const float*)d_in[12];
    const float* b2   = (const float*)d_in[13];
    float* out = (float*)d_out;

    char* ws = (char*)d_ws;
    _Float16* xh = (_Float16*)ws;                         // 8 MB
    _Float16* fA = (_Float16*)(ws + (8u << 20));          // 8 MB
    _Float16* fB = (_Float16*)(ws + (16u << 20));         // 8 MB
    half8* w2p   = (half8*)(ws + (24u << 20));            // 221184 B
    float* b2p   = (float*)(ws + (24u << 20) + 221184);   // 1728 B
    half8* wpk   = (half8*)(ws + (24u << 20) + 221184 + 1728);  // 20480 B

    xcvt<<<1024, 256, 0, stream>>>(x, xh);
    pack_all<<<59, 256, 0, stream>>>(w2, b2, w2p, b2p, c0w, c1w, c2w, c3w, wpk);

    conv_mfma<<<1024, 256, 0, stream>>>(xh, wpk,         c0b, fA);
    conv_mfma<<<1024, 256, 0, stream>>>(fA, wpk + 320,   c1b, fB);
    conv_mfma<<<1024, 256, 0, stream>>>(fB, wpk + 640,   c2b, fA);
    conv_mfma<<<1024, 256, 0, stream>>>(fA, wpk + 960,   c3b, fB);

    mlp_lc_mfma<<<4096, 512, 0, stream>>>(pos, w1, b1, w2p, b2p, fB, out);
}